// Round 5
// baseline (131.258 us; speedup 1.0000x reference)
//
#include <hip/hip_runtime.h>

// ImprovedBilateralFilter3D — 96^3 fp32, fused single kernel, v3.
//
// Per block: 32x8x4 output tile (1024 voxels), 256 threads.
//   Stage A: 36x12x8 volume tile (halo 2) -> LDS, zero outside bounds.
//   Stage B: Sobel over 34x10x6 (tile + halo 1), computed in REGISTERS
//            (pairs of x-adjacent voxels share loads), then written as
//            float4{gh,gw,gd,val} OVER the volume tile (LDS union) after
//            a barrier. LDS = max(13.8, 32.6) = 32.6 KB -> 4 blocks/CU.
//   Stage C: bilateral; each thread owns a z-column of 4 voxels; 6 shared
//            z-planes x 9 neighbors = 54 ds_read_b128 for 4 outputs.
//            Spatial term folded into a compile-time constant per offset.

#define NV 96
#define NV2 (NV * NV)

#define TX 32
#define TY 8
#define TZ 4
#define VX (TX + 4)  // 36
#define VY (TY + 4)  // 12
#define VZ (TZ + 4)  // 8
#define GX (TX + 2)  // 34
#define GY (TY + 2)  // 10
#define GZ (TZ + 2)  // 6
#define NVOL (VX * VY * VZ)         // 3456
#define NPAIR (GZ * GY * (GX / 2))  // 1020

__global__ __launch_bounds__(256, 4) void fused_bilateral_kernel(
    const float* __restrict__ vol, float* __restrict__ out) {
    __shared__ union {
        float sv[VZ][VY][VX];    // raw volume (zero-padded), stages A/B
        float4 sq[GZ][GY][GX];   // {gh, gw, gd, val}, stage C
    } u;

    const int X0 = blockIdx.x * TX;
    const int Y0 = blockIdx.y * TY;
    const int Z0 = blockIdx.z * TZ;
    const int t = threadIdx.x;

    // ---- Stage A: volume tile + halo 2, zero outside global bounds ----
    for (int li = t; li < NVOL; li += 256) {
        int lx = li % VX;
        int lyz = li / VX;
        int ly = lyz % VY;
        int lz = lyz / VY;
        int gx = X0 - 2 + lx;
        int gy = Y0 - 2 + ly;
        int gz = Z0 - 2 + lz;
        float v = 0.0f;
        if (gx >= 0 && gx < NV && gy >= 0 && gy < NV && gz >= 0 && gz < NV)
            v = vol[gz * NV2 + gy * NV + gx];
        u.sv[lz][ly][lx] = v;
    }
    __syncthreads();

    // ---- Stage B: Sobel (cross-corr, zero pad) into registers ----
    // Pair p covers grad-local x = 2p, 2p+1; vol-local of grad-local g is g+1.
    float4 r0[4], r1[4];
#pragma unroll
    for (int k = 0; k < 4; ++k) {
        int li = t + k * 256;
        int lp = (li < NPAIR) ? li : 0;  // inactive lanes compute a dummy
        int lxp = lp % 17;
        int lyy = (lp / 17) % GY;
        int lzz = lp / (17 * GY);
        int lx = lxp * 2;
        float gh0 = 0.f, gw0 = 0.f, gd0 = 0.f;
        float gh1 = 0.f, gw1 = 0.f, gd1 = 0.f;
        float cv0 = 0.f, cv1 = 0.f;
#pragma unroll
        for (int a = 0; a < 3; ++a) {
            const float sma = (a == 1) ? 0.5f : 0.25f;
            const float dva = (a == 0) ? 1.0f : ((a == 2) ? -1.0f : 0.0f);
#pragma unroll
            for (int b = 0; b < 3; ++b) {
                const float smb = (b == 1) ? 0.5f : 0.25f;
                const float dvb = (b == 0) ? 1.0f : ((b == 2) ? -1.0f : 0.0f);
                float v0 = u.sv[lzz + a][lyy + b][lx + 0];
                float v1 = u.sv[lzz + a][lyy + b][lx + 1];
                float v2 = u.sv[lzz + a][lyy + b][lx + 2];
                float v3 = u.sv[lzz + a][lyy + b][lx + 3];
                float xs0 = 0.25f * v0 + 0.5f * v1 + 0.25f * v2;
                float xd0 = v0 - v2;
                float xs1 = 0.25f * v1 + 0.5f * v2 + 0.25f * v3;
                float xd1 = v1 - v3;
                gh0 += dva * smb * xs0;
                gw0 += sma * dvb * xs0;
                gd0 += sma * smb * xd0;
                gh1 += dva * smb * xs1;
                gw1 += sma * dvb * xs1;
                gd1 += sma * smb * xd1;
                if (a == 1 && b == 1) { cv0 = v1; cv1 = v2; }
            }
        }
        r0[k] = make_float4(gh0, gw0, gd0, cv0);
        r1[k] = make_float4(gh1, gw1, gd1, cv1);
    }
    __syncthreads();  // all sv reads done before sq overwrites

#pragma unroll
    for (int k = 0; k < 4; ++k) {
        int li = t + k * 256;
        if (li < NPAIR) {
            int lxp = li % 17;
            int lyy = (li / 17) % GY;
            int lzz = li / (17 * GY);
            u.sq[lzz][lyy][lxp * 2] = r0[k];
            u.sq[lzz][lyy][lxp * 2 + 1] = r1[k];
        }
    }
    __syncthreads();

    // ---- Stage C: bilateral, z-column of 4 voxels per thread ----
    const int tx = t & 31;
    const int ty = t >> 5;  // 0..7
    const int ox = X0 + tx;
    const int oy = Y0 + ty;

    const float inv2sr = 1.0f / (2.0f * 1.2f * 1.2f);
    const float inv2sd = 1.0f / (2.0f * 120.0f * 120.0f);

    // center packed grads: grad-local z = k+1 for output z = Z0+k
    const float4 c0 = u.sq[1][ty + 1][tx + 1];
    const float4 c1 = u.sq[2][ty + 1][tx + 1];
    const float4 c2 = u.sq[3][ty + 1][tx + 1];
    const float4 c3 = u.sq[4][ty + 1][tx + 1];

    int nx[3], ny[3], nz[6];
#pragma unroll
    for (int d = 0; d < 3; ++d) {
        nx[d] = min(max(ox + d - 1, 0), NV - 1) - (X0 - 1);
        ny[d] = min(max(oy + d - 1, 0), NV - 1) - (Y0 - 1);
    }
#pragma unroll
    for (int p = 0; p < 6; ++p)
        nz[p] = min(max(Z0 + p - 1, 0), NV - 1) - (Z0 - 1);

    float num[4] = {0.f, 0.f, 0.f, 0.f};
    float den[4] = {0.f, 0.f, 0.f, 0.f};

#pragma unroll
    for (int p = 0; p < 6; ++p) {  // absolute plane Z0-1+p
#pragma unroll
        for (int iy = 0; iy < 3; ++iy) {
#pragma unroll
            for (int ix = 0; ix < 3; ++ix) {
                float4 q = u.sq[nz[p]][ny[iy]][nx[ix]];
#pragma unroll
                for (int k = 0; k < 4; ++k) {
                    const int dz = p - 1 - k;
                    if (dz >= -1 && dz <= 1) {
                        const float SD =
                            -(float)(dz * dz + (iy - 1) * (iy - 1) +
                                     (ix - 1) * (ix - 1)) * inv2sd;
                        float4 c = (k == 0) ? c0 : (k == 1) ? c1
                                 : (k == 2) ? c2 : c3;
                        float a = c.x - q.x, b = c.y - q.y, e = c.z - q.z;
                        float g = a * a + b * b + e * e;
                        float w = __expf(SD - g * inv2sr);
                        num[k] += w * q.w;
                        den[k] += w;
                    }
                }
            }
        }
    }

#pragma unroll
    for (int k = 0; k < 4; ++k)
        out[(Z0 + k) * NV2 + oy * NV + ox] = num[k] / fmaxf(den[k], 1e-8f);
}

extern "C" void kernel_launch(void* const* d_in, const int* in_sizes, int n_in,
                              void* d_out, int out_size, void* d_ws, size_t ws_size,
                              hipStream_t stream) {
    const float* vol = (const float*)d_in[0];
    float* out = (float*)d_out;

    dim3 grid(NV / TX, NV / TY, NV / TZ);  // 3 x 12 x 24 = 864 blocks
    fused_bilateral_kernel<<<grid, dim3(256), 0, stream>>>(vol, out);
}

// Round 6
// 71.197 us; speedup vs baseline: 1.8436x; 1.8436x over previous
//
#include <hip/hip_runtime.h>

// ImprovedBilateralFilter3D — 96^3 fp32, fused single kernel, v4.
//
// Per block: 32x4x4 output tile (512 voxels), 256 threads. No reg buffering
// across barriers (r5's union+reg scheme caused 270 MB of scratch spill
// traffic -> 81 us; reverted).
//   Stage A: 36x8x8 volume tile (halo 2) -> LDS sv, zero outside bounds.
//   Stage B: separable Sobel, plane-sweep: one thread per (x,y) of the
//            34x6 grad patch marches the 8 z-planes; per plane computes
//            sm(x)sm(y), sm(x)dy, dx sm(y) partials from 9 LDS reads and
//            combines across z in rolling registers. Writes
//            float4{gh,gw,gd,val} into sq.  (72 b32 reads/thread vs 135.)
//   Stage C: bilateral; 2 voxels/thread (z, z+2) sharing the middle planes:
//            45 ds_read_b128. Spatial weight folded per-offset at compile
//            time into the single __expf.
// LDS: 9216 (sv) + 19584 (sq) = 28.8 KB -> 5 blocks/CU.

#define NV 96
#define NV2 (NV * NV)

#define TX 32
#define TY 4
#define TZ 4
#define VX (TX + 4)  // 36
#define VY (TY + 4)  // 8
#define VZ (TZ + 4)  // 8
#define GX (TX + 2)  // 34
#define GY (TY + 2)  // 6
#define GZ (TZ + 2)  // 6
#define NVOL (VX * VY * VZ)  // 2304

__global__ __launch_bounds__(256) void fused_bilateral_kernel(
    const float* __restrict__ vol, float* __restrict__ out) {
    __shared__ float sv[VZ][VY][VX];   // raw volume, zero-padded
    __shared__ float4 sq[GZ][GY][GX];  // {gh, gw, gd, val}

    const int X0 = blockIdx.x * TX;
    const int Y0 = blockIdx.y * TY;
    const int Z0 = blockIdx.z * TZ;
    const int t = threadIdx.x;

    // ---- Stage A: volume tile + halo 2, zero outside global bounds ----
    for (int li = t; li < NVOL; li += 256) {
        int lx = li % VX;
        int lyz = li / VX;
        int ly = lyz % VY;
        int lz = lyz / VY;
        int gx = X0 - 2 + lx;
        int gy = Y0 - 2 + ly;
        int gz = Z0 - 2 + lz;
        float v = 0.0f;
        if (gx >= 0 && gx < NV && gy >= 0 && gy < NV && gz >= 0 && gz < NV)
            v = vol[gz * NV2 + gy * NV + gx];
        sv[lz][ly][lx] = v;
    }
    __syncthreads();

    // ---- Stage B: separable Sobel, z plane-sweep ----
    // Thread t < 204 owns grad-local xy (gx_, gy_); center vol-local
    // coords are (gx_+1, gy_+1, p-1) when emitting at plane p.
    if (t < GX * GY) {
        const int gx_ = t % GX;
        const int gy_ = t / GX;
        float s0 = 0.f, s1 = 0.f, s2 = 0.f;  // sm_y (x) sm_x partial per plane
        float w0 = 0.f, w1 = 0.f, w2 = 0.f;  // dy (x) sm_x partial
        float u0 = 0.f, u1 = 0.f, u2 = 0.f;  // sm_y (x) dx partial
        float v11p = 0.f;                    // center value of previous plane
#pragma unroll
        for (int p = 0; p < VZ; ++p) {
            float a00 = sv[p][gy_ + 0][gx_ + 0];
            float a01 = sv[p][gy_ + 0][gx_ + 1];
            float a02 = sv[p][gy_ + 0][gx_ + 2];
            float a10 = sv[p][gy_ + 1][gx_ + 0];
            float a11 = sv[p][gy_ + 1][gx_ + 1];
            float a12 = sv[p][gy_ + 1][gx_ + 2];
            float a20 = sv[p][gy_ + 2][gx_ + 0];
            float a21 = sv[p][gy_ + 2][gx_ + 1];
            float a22 = sv[p][gy_ + 2][gx_ + 2];
            // x-smoothed rows (y = gy_+0,1,2)
            float r0 = 0.25f * a00 + 0.5f * a01 + 0.25f * a02;
            float r1 = 0.25f * a10 + 0.5f * a11 + 0.25f * a12;
            float r2 = 0.25f * a20 + 0.5f * a21 + 0.25f * a22;
            float sxy = 0.25f * r0 + 0.5f * r1 + 0.25f * r2;  // sm_y sm_x
            float dyx = r0 - r2;                              // dy sm_x
            float dx0 = a00 - a02;
            float dx1 = a10 - a12;
            float dx2 = a20 - a22;
            float dxs = 0.25f * dx0 + 0.5f * dx1 + 0.25f * dx2;  // sm_y dx
            // rotate (compile-time after unroll)
            s0 = s1; s1 = s2; s2 = sxy;
            w0 = w1; w1 = w2; w2 = dyx;
            u0 = u1; u1 = u2; u2 = dxs;
            if (p >= 2) {
                // grad voxel at grad-local z = p-2 (vol planes p-2,p-1,p)
                float gh = s0 - s2;                              // deriv_z
                float gw = 0.25f * w0 + 0.5f * w1 + 0.25f * w2;  // sm_z dy
                float gd = 0.25f * u0 + 0.5f * u1 + 0.25f * u2;  // sm_z dx
                sq[p - 2][gy_][gx_] = make_float4(gh, gw, gd, v11p);
            }
            v11p = a11;  // becomes the center value for next emit
        }
    }
    __syncthreads();

    // ---- Stage C: bilateral, 2 output voxels per thread (z and z+2) ----
    const int tx = t & 31;
    const int ty = (t >> 5) & 3;
    const int tzh = t >> 7;  // 0..1

    const float inv2sd = 1.0f / (2.0f * 120.0f * 120.0f);
    const float inv2sr = 1.0f / (2.0f * 1.2f * 1.2f);

    const int ox = X0 + tx;
    const int oy = Y0 + ty;
    const int oz0 = Z0 + tzh;
    const int oz1 = oz0 + 2;

    // center packed grads: grad-local = tile-local + 1
    const float4 c0 = sq[tzh + 1][ty + 1][tx + 1];
    const float4 c1 = sq[tzh + 3][ty + 1][tx + 1];

    int nx[3], ny[3], nz[5];
#pragma unroll
    for (int d = 0; d < 3; ++d) {
        nx[d] = min(max(ox + d - 1, 0), NV - 1) - (X0 - 1);
        ny[d] = min(max(oy + d - 1, 0), NV - 1) - (Y0 - 1);
    }
#pragma unroll
    for (int p = 0; p < 5; ++p)
        nz[p] = min(max(oz0 + p - 1, 0), NV - 1) - (Z0 - 1);

    float num0 = 0.0f, den0 = 0.0f, num1 = 0.0f, den1 = 0.0f;

#pragma unroll
    for (int p = 0; p < 5; ++p) {  // absolute plane oz0-1+p
#pragma unroll
        for (int iy = 0; iy < 3; ++iy) {
#pragma unroll
            for (int ix = 0; ix < 3; ++ix) {
                float4 q = sq[nz[p]][ny[iy]][nx[ix]];
                if (p <= 2) {  // voxel0: dz = p-1
                    const float sdc =
                        (float)((p - 1) * (p - 1) + (iy - 1) * (iy - 1) +
                                (ix - 1) * (ix - 1)) * inv2sd;
                    float a = c0.x - q.x, b = c0.y - q.y, e = c0.z - q.z;
                    float g = a * a + b * b + e * e;
                    float w = __expf(-(sdc + g * inv2sr));
                    num0 += w * q.w;
                    den0 += w;
                }
                if (p >= 2) {  // voxel1: dz = p-3
                    const float sdc =
                        (float)((p - 3) * (p - 3) + (iy - 1) * (iy - 1) +
                                (ix - 1) * (ix - 1)) * inv2sd;
                    float a = c1.x - q.x, b = c1.y - q.y, e = c1.z - q.z;
                    float g = a * a + b * b + e * e;
                    float w = __expf(-(sdc + g * inv2sr));
                    num1 += w * q.w;
                    den1 += w;
                }
            }
        }
    }

    out[oz0 * NV2 + oy * NV + ox] = num0 / fmaxf(den0, 1e-8f);
    out[oz1 * NV2 + oy * NV + ox] = num1 / fmaxf(den1, 1e-8f);
}

extern "C" void kernel_launch(void* const* d_in, const int* in_sizes, int n_in,
                              void* d_out, int out_size, void* d_ws, size_t ws_size,
                              hipStream_t stream) {
    const float* vol = (const float*)d_in[0];
    float* out = (float*)d_out;

    dim3 grid(NV / TX, NV / TY, NV / TZ);  // 3 x 24 x 24 = 1728 blocks
    fused_bilateral_kernel<<<grid, dim3(256), 0, stream>>>(vol, out);
}